// Round 7
// baseline (383.471 us; speedup 1.0000x reference)
//
#include <hip/hip_runtime.h>
#include <hip/hip_bf16.h>

// Problem constants
#define NB 2
#define NL 2048
#define ND 1024
#define NH 16
#define NDH 64
#define NM (NB*NL)   // 4096 rows total

typedef unsigned short u16;
typedef __attribute__((ext_vector_type(8))) short short8;   // 8 bf16 in 4 VGPRs
typedef __attribute__((ext_vector_type(4))) float floatx4;  // MFMA accumulator

// fp32 -> bf16 round-to-nearest-even (bit trick)
__device__ __forceinline__ u16 f2bf(float f) {
  union { float f; unsigned int u; } v; v.f = f;
  unsigned int r = v.u + 0x7FFF + ((v.u >> 16) & 1);
  return (u16)(r >> 16);
}

// async global->LDS 16B (m97 lever). LDS dest is wave-uniform base + lane*16.
__device__ __forceinline__ void async_cp16(u16* lds, const u16* g) {
  __builtin_amdgcn_global_load_lds(
      (const __attribute__((address_space(1))) void*)g,
      (__attribute__((address_space(3))) void*)lds, 16, 0, 0);
}

// lane <-> lane^1 exchange on the VALU (DPP quad_perm [1,0,3,2]) — no LDS pipe
__device__ __forceinline__ unsigned dpp_xor1(unsigned v) {
  return (unsigned)__builtin_amdgcn_mov_dpp((int)v, 0xB1, 0xF, 0xF, true);
}

// ---------------------------------------------------------------------------
// Pre-convert fp32 -> bf16: Wq,Wk,Wv,Wp (1M elems each) -> Wb, x (4M) -> xb.
// ---------------------------------------------------------------------------
__global__ __launch_bounds__(256)
void cvt_all(const float* __restrict__ wq, const float* __restrict__ wk,
             const float* __restrict__ wv, const float* __restrict__ wp,
             const float* __restrict__ x,
             u16* __restrict__ ow, u16* __restrict__ ox)
{
  const int per4 = ND * ND / 4;            // 262144 float4 per weight matrix
  const int tot  = 4 * per4 + NM * ND / 4; // + 1048576 for x
  for (int t = blockIdx.x * 256 + threadIdx.x; t < tot; t += gridDim.x * 256) {
    const float* src; uint2* dst; int off;
    if (t < 4 * per4) {
      int w = t >> 18; off = t & (per4 - 1);
      src = (w == 0) ? wq : (w == 1) ? wk : (w == 2) ? wv : wp;
      dst = (uint2*)(ow + (size_t)w * ND * ND);
    } else {
      off = t - 4 * per4; src = x; dst = (uint2*)ox;
    }
    float4 f = ((const float4*)src)[off];
    u16 h[4] = { f2bf(f.x), f2bf(f.y), f2bf(f.z), f2bf(f.w) };
    dst[off] = *(const uint2*)h;
  }
}

// ---------------------------------------------------------------------------
// GEMM: C[m][n] = (sum_k A[m][k] * W[n][k] + bias[n]) * scale_z
// A,W: bf16, staged via async global_load_lds (m97 structure).
// C: fp32 or bf16. blockIdx.z selects weight/out set; scale0 applies to z==0.
// 128x128 tile, BK=32, 256 threads (4 waves as 2x2 of 64x64), MFMA 16x16x32.
// ---------------------------------------------------------------------------
#define BM 128
#define BN 128
#define BK 32
#define LDT 32   // LDS tile row stride in bf16 elems (contiguous for async cp)

template<bool C_F32>
__global__ __launch_bounds__(256)
void gemm_bt_bias(const u16* __restrict__ A,
                  const u16* __restrict__ W0, const u16* __restrict__ W1, const u16* __restrict__ W2,
                  const float* __restrict__ B0, const float* __restrict__ B1, const float* __restrict__ B2,
                  void* __restrict__ C0, void* __restrict__ C1, void* __restrict__ C2,
                  float scale0)
{
  const int z = blockIdx.z;
  const u16* W    = (z == 0) ? W0 : (z == 1) ? W1 : W2;
  const float* Bi = (z == 0) ? B0 : (z == 1) ? B1 : B2;
  void* C         = (z == 0) ? C0 : (z == 1) ? C1 : C2;
  const float sc  = (z == 0) ? scale0 : 1.0f;

  const int n0 = blockIdx.x * BN;
  const int m0 = blockIdx.y * BM;
  const int tid  = threadIdx.x;
  const int lane = tid & 63;
  const int wave = tid >> 6;
  const int wm = (wave >> 1) * 64;
  const int wn = (wave & 1) * 64;
  const int quad = lane >> 4;
  const int l16  = lane & 15;

  __shared__ u16 As[BM * LDT];
  __shared__ u16 Bs[BN * LDT];

  floatx4 acc[4][4];
#pragma unroll
  for (int i = 0; i < 4; ++i)
#pragma unroll
    for (int j = 0; j < 4; ++j)
      acc[i][j] = (floatx4){0.f, 0.f, 0.f, 0.f};

  for (int k0 = 0; k0 < ND; k0 += BK) {
#pragma unroll
    for (int it = 0; it < 2; ++it) {
      int idx = tid + it * 256;            // 0..511
      int rr  = idx >> 2;                  // 0..127
      int c8  = (idx & 3) << 3;            // 0,8,16,24
      async_cp16(&Bs[idx * 8], &W[(size_t)(n0 + rr) * ND + k0 + c8]);
      async_cp16(&As[idx * 8], &A[(size_t)(m0 + rr) * ND + k0 + c8]);
    }
    __syncthreads();

    short8 af[4], bfr[4];
#pragma unroll
    for (int i = 0; i < 4; ++i)
      af[i] = *(const short8*)&As[(wm + i * 16 + l16) * LDT + quad * 8];
#pragma unroll
    for (int j = 0; j < 4; ++j)
      bfr[j] = *(const short8*)&Bs[(wn + j * 16 + l16) * LDT + quad * 8];

#pragma unroll
    for (int i = 0; i < 4; ++i)
#pragma unroll
      for (int j = 0; j < 4; ++j)
        acc[i][j] = __builtin_amdgcn_mfma_f32_16x16x32_bf16(af[i], bfr[j], acc[i][j], 0, 0, 0);
    __syncthreads();
  }

  // Epilogue. D map: row=(lane>>4)*4+r, col=lane&15.
#pragma unroll
  for (int j = 0; j < 4; ++j) {
    const int ncol = n0 + wn + j * 16 + l16;
    const float bv = Bi[ncol];
#pragma unroll
    for (int i = 0; i < 4; ++i) {
      const int mbase = m0 + wm + i * 16 + quad * 4;
#pragma unroll
      for (int r2 = 0; r2 < 4; ++r2) {
        float v = (acc[i][j][r2] + bv) * sc;
        if (C_F32) ((float*)C)[(size_t)(mbase + r2) * ND + ncol] = v;
        else       ((u16*)C)[(size_t)(mbase + r2) * ND + ncol] = f2bf(v);
      }
    }
  }
}

// ---------------------------------------------------------------------------
// V transpose: V [B,L,H,DH] bf16 -> VT [B,H,DH,L] bf16. 64x64 tiles via LDS.
// TSTR=66: write-phase column reads land 2-way on banks (free).
// ---------------------------------------------------------------------------
#define TSTR 66
__global__ __launch_bounds__(256)
void vtrans(const u16* __restrict__ V, u16* __restrict__ VT)
{
  const int lt = blockIdx.x;        // l tile 0..31
  const int bh = blockIdx.y;
  const int b = bh >> 4, h = bh & 15;
  const int l0 = lt * 64;
  const int tid = threadIdx.x;
  __shared__ u16 Ls[64][TSTR];
#pragma unroll
  for (int p = 0; p < 2; ++p) {
    int idx = tid + p * 256;
    int r = idx >> 3, c = (idx & 7) << 3;
    *(uint4*)&Ls[r][c] = *(const uint4*)&V[(size_t)(b * NL + l0 + r) * ND + h * NDH + c];
  }
  __syncthreads();
#pragma unroll
  for (int p = 0; p < 2; ++p) {
    int idx = tid + p * 256;
    int lg = idx & 7, d = idx >> 3;   // lg = l-subgroup, d = dim 0..63
    u16 tb[8];
#pragma unroll
    for (int e = 0; e < 8; ++e) tb[e] = Ls[lg * 8 + e][d];
    *(uint4*)&VT[((size_t)(b * NH + h) * NDH + d) * NL + l0 + lg * 8] = *(const uint4*)tb;
  }
}

// ---------------------------------------------------------------------------
// MFMA flash attention, barrier-free. No-max softmax (scores bounded).
// K frags and VT frags load DIRECTLY from global (layout matches MFMA B
// fragment: lane l16 -> row, quad*8 -> 16B contiguous; all 4 waves hit the
// same L1 lines). LDS holds only the P C->A-layout round-trip, per-wave
// private -> ZERO __syncthreads in the kernel. l via MFMA ones-column.
// Block = 256 threads (4 waves), one (b,h), 64-row Q tile; wave owns 16 rows.
// Y aliases Q (wave reads its Q rows first, writes the same rows last).
// ---------------------------------------------------------------------------
#define KC 64
#define PSTR 72   // padded LDS row stride (bf16)

__global__ __launch_bounds__(256)
void attn_mfma(const u16* __restrict__ Q, const u16* __restrict__ K,
               const u16* __restrict__ VT, const int* __restrict__ msk,
               u16* __restrict__ Y)
{
  const int qt = gridDim.x - 1 - blockIdx.x;  // big tiles dispatched first
  const int bh = blockIdx.y;
  const int b = bh >> 4;
  const int h = bh & 15;
  const int q0 = qt * 64;
  const int tid  = threadIdx.x;
  const int lane = tid & 63;
  const int wave = tid >> 6;
  const int wq   = wave * 16;      // wave's q-row offset in tile
  const int quad = lane >> 4;
  const int l16  = lane & 15;

  __shared__ u16 Ps[64][PSTR];     // [q_local][key] — per-wave disjoint rows

  const u16* Kbase  = K  + (size_t)b * NL * ND + h * NDH;
  const u16* VTbase = VT + (size_t)(b * NH + h) * NDH * NL;
  const int* mbase  = msk + b * NL;

  // Q fragments (A-layout: m=l16, k=quad*8+j), pre-scaled by 1/8 in GEMM1.
  short8 qf[2];
#pragma unroll
  for (int kk = 0; kk < 2; ++kk)
    qf[kk] = *(const short8*)&Q[(size_t)(b * NL + q0 + wq + l16) * ND
                                + h * NDH + kk * 32 + quad * 8];

  // Constant ones B-fragment: B[n=l16][k] = (n==0) ? 1.0bf : 0
  short8 onesf;
  {
    const short ov = (l16 == 0) ? (short)0x3F80 : (short)0;
#pragma unroll
    for (int e = 0; e < 8; ++e) onesf[e] = ov;
  }

  floatx4 o[4];                    // output accum, un-normalized
#pragma unroll
  for (int ot = 0; ot < 4; ++ot) o[ot] = (floatx4){0.f, 0.f, 0.f, 0.f};
  floatx4 lacc = (floatx4){0.f, 0.f, 0.f, 0.f};   // col 0 holds row-sum l

  const int odd = l16 & 1;
  for (int kc = 0; kc <= qt; ++kc) {
    const int k0 = kc * KC;

    // ---- S = Q K^T, K frags straight from global ----
    floatx4 s[4];
#pragma unroll
    for (int ct = 0; ct < 4; ++ct) {
      const u16* kr = Kbase + (size_t)(k0 + ct * 16 + l16) * ND;
      short8 kf0 = *(const short8*)(kr + quad * 8);
      short8 kf1 = *(const short8*)(kr + 32 + quad * 8);
      floatx4 a = (floatx4){0.f, 0.f, 0.f, 0.f};
      a = __builtin_amdgcn_mfma_f32_16x16x32_bf16(qf[0], kf0, a, 0, 0, 0);
      a = __builtin_amdgcn_mfma_f32_16x16x32_bf16(qf[1], kf1, a, 0, 0, 0);
      s[ct] = a;
    }

    // ---- P = pad * causal * exp(S); packed b32 LDS writes (own rows) ----
    const bool diag = (kc == qt);
    const int rowb = q0 + wq + quad * 4;
#pragma unroll
    for (int ct = 0; ct < 4; ++ct) {
      const int col = k0 + ct * 16 + l16;
      const float pmul = (float)mbase[col];
      unsigned bb[4];
#pragma unroll
      for (int r2 = 0; r2 < 4; ++r2) {
        float p = pmul * __expf(s[ct][r2]);
        if (diag) p = (col > rowb + r2) ? 0.f : p;
        bb[r2] = (unsigned)f2bf(p);
      }
      unsigned n0v = dpp_xor1(bb[0]), n1v = dpp_xor1(bb[1]);
      unsigned n2v = dpp_xor1(bb[2]), n3v = dpp_xor1(bb[3]);
      const int colb  = ct * 16 + (l16 & ~1);
      const int row01 = wq + quad * 4 + odd;
      unsigned d01 = odd ? (n1v | (bb[1] << 16)) : (bb[0] | (n0v << 16));
      unsigned d23 = odd ? (n3v | (bb[3] << 16)) : (bb[2] | (n2v << 16));
      *(unsigned*)&Ps[row01][colb]     = d01;
      *(unsigned*)&Ps[row01 + 2][colb] = d23;
    }

    // ---- O += P V (VT frags straight from global); l += P * ones ----
#pragma unroll
    for (int kk = 0; kk < 2; ++kk) {
      short8 pf = *(const short8*)&Ps[wq + l16][kk * 32 + quad * 8];
#pragma unroll
      for (int ot = 0; ot < 4; ++ot) {
        short8 vf = *(const short8*)(VTbase + (size_t)(ot * 16 + l16) * NL
                                     + k0 + kk * 32 + quad * 8);
        o[ot] = __builtin_amdgcn_mfma_f32_16x16x32_bf16(pf, vf, o[ot], 0, 0, 0);
      }
      lacc = __builtin_amdgcn_mfma_f32_16x16x32_bf16(pf, onesf, lacc, 0, 0, 0);
    }
  }

  // ---- epilogue: O / l -> Y (aliases Q; our rows only, reads done) ----
  float inv[4];
#pragma unroll
  for (int r2 = 0; r2 < 4; ++r2) {
    const float l = __shfl(lacc[r2], quad << 4);   // col 0 of the l-tile
    inv[r2] = 1.0f / l;
  }
#pragma unroll
  for (int ot = 0; ot < 4; ++ot)
#pragma unroll
    for (int r2 = 0; r2 < 4; ++r2) {
      const int row = q0 + wq + quad * 4 + r2;
      Y[(size_t)(b * NL + row) * ND + h * NDH + ot * 16 + l16] = f2bf(o[ot][r2] * inv[r2]);
    }
}

// ---------------------------------------------------------------------------
extern "C" void kernel_launch(void* const* d_in, const int* in_sizes, int n_in,
                              void* d_out, int out_size, void* d_ws, size_t ws_size,
                              hipStream_t stream) {
  const float* x  = (const float*)d_in[0];
  const int*   m  = (const int*)d_in[1];
  const float* Wq = (const float*)d_in[2];
  const float* bq = (const float*)d_in[3];
  const float* Wk = (const float*)d_in[4];
  const float* bk = (const float*)d_in[5];
  const float* Wv = (const float*)d_in[6];
  const float* bv = (const float*)d_in[7];
  const float* Wp = (const float*)d_in[8];
  const float* bp = (const float*)d_in[9];
  float* out = (float*)d_out;

  // Workspace (32 MiB): Q|Y alias (8) + K (8) + V (8) + Wb bf16 x4 (8)
  // d_out (16 MiB fp32) moonlights as: xb (bf16 x, first 8 MiB) + VTb (bf16
  // V-transpose, second 8 MiB). Both are dead by the time the final proj GEMM
  // overwrites d_out (stream-ordered).
  const size_t per = (size_t)NM * ND;
  u16* Qb = (u16*)d_ws;
  u16* Kb = Qb + per;
  u16* Vb = Kb + per;
  u16* Wb = Vb + per;              // 4 * ND*ND bf16, contiguous
  u16* Yb = Qb;                    // alias
  u16* xb = (u16*)d_out;
  u16* VTb = xb + per;

  // 0) fp32 -> bf16 for weights and x
  cvt_all<<<2048, 256, 0, stream>>>(Wq, Wk, Wv, Wp, x, Wb, xb);

  // 1) QKV projections (all-bf16 async staging; Q pre-scaled by 1/8)
  dim3 gq(ND / BN, NM / BM, 3);
  gemm_bt_bias<false><<<gq, 256, 0, stream>>>(
      xb, Wb, Wb + (size_t)ND * ND, Wb + 2 * (size_t)ND * ND,
      bq, bk, bv, (void*)Qb, (void*)Kb, (void*)Vb, 0.125f);

  // 1b) V -> VT (B,H,DH,L) for direct-from-global PV fragments
  vtrans<<<dim3(NL / 64, NB * NH), 256, 0, stream>>>(Vb, VTb);

  // 2) MFMA flash attention, barrier-free (Y aliases Q)
  attn_mfma<<<dim3(NL / 64, NB * NH), 256, 0, stream>>>(Qb, Kb, VTb, m, Yb);

  // 3) Output projection (A=Y bf16, C=fp32 d_out)
  dim3 gp(ND / BN, NM / BM, 1);
  const u16* Wpb = Wb + 3 * (size_t)ND * ND;
  gemm_bt_bias<true><<<gp, 256, 0, stream>>>(
      Yb, Wpb, Wpb, Wpb, bp, bp, bp,
      (void*)out, (void*)out, (void*)out, 1.0f);
}

// Round 8
// 215.739 us; speedup vs baseline: 1.7775x; 1.7775x over previous
//
#include <hip/hip_runtime.h>
#include <hip/hip_bf16.h>

// Problem constants
#define NB 2
#define NL 2048
#define ND 1024
#define NH 16
#define NDH 64
#define NM (NB*NL)   // 4096 rows total

typedef unsigned short u16;
typedef __attribute__((ext_vector_type(8))) short short8;   // 8 bf16 in 4 VGPRs
typedef __attribute__((ext_vector_type(4))) float floatx4;  // MFMA accumulator

// fp32 -> bf16 round-to-nearest-even (bit trick)
__device__ __forceinline__ u16 f2bf(float f) {
  union { float f; unsigned int u; } v; v.f = f;
  unsigned int r = v.u + 0x7FFF + ((v.u >> 16) & 1);
  return (u16)(r >> 16);
}

// async global->LDS 16B (m97 lever). LDS dest is wave-uniform base + lane*16.
__device__ __forceinline__ void async_cp16(u16* lds, const u16* g) {
  __builtin_amdgcn_global_load_lds(
      (const __attribute__((address_space(1))) void*)g,
      (__attribute__((address_space(3))) void*)lds, 16, 0, 0);
}

// lane <-> lane^1 exchange on the VALU (DPP quad_perm [1,0,3,2]) — no LDS pipe
__device__ __forceinline__ unsigned dpp_xor1(unsigned v) {
  return (unsigned)__builtin_amdgcn_mov_dpp((int)v, 0xB1, 0xF, 0xF, true);
}

// ---------------------------------------------------------------------------
// Pre-convert fp32 -> bf16: Wq,Wk,Wv,Wp (1M elems each) -> Wb, x (4M) -> xb.
// ---------------------------------------------------------------------------
__global__ __launch_bounds__(256)
void cvt_all(const float* __restrict__ wq, const float* __restrict__ wk,
             const float* __restrict__ wv, const float* __restrict__ wp,
             const float* __restrict__ x,
             u16* __restrict__ ow, u16* __restrict__ ox)
{
  const int per4 = ND * ND / 4;            // 262144 float4 per weight matrix
  const int tot  = 4 * per4 + NM * ND / 4; // + 1048576 for x
  for (int t = blockIdx.x * 256 + threadIdx.x; t < tot; t += gridDim.x * 256) {
    const float* src; uint2* dst; int off;
    if (t < 4 * per4) {
      int w = t >> 18; off = t & (per4 - 1);
      src = (w == 0) ? wq : (w == 1) ? wk : (w == 2) ? wv : wp;
      dst = (uint2*)(ow + (size_t)w * ND * ND);
    } else {
      off = t - 4 * per4; src = x; dst = (uint2*)ox;
    }
    float4 f = ((const float4*)src)[off];
    u16 h[4] = { f2bf(f.x), f2bf(f.y), f2bf(f.z), f2bf(f.w) };
    dst[off] = *(const uint2*)h;
  }
}

// ---------------------------------------------------------------------------
// GEMM: C[m][n] = (sum_k A[m][k] * W[n][k] + bias[n]) * scale_z
// A,W: bf16, staged via async global_load_lds (m97 structure).
// C: fp32 or bf16. blockIdx.z selects weight/out set; scale0 applies to z==0.
// 128x128 tile, BK=32, 256 threads (4 waves as 2x2 of 64x64), MFMA 16x16x32.
// ---------------------------------------------------------------------------
#define BM 128
#define BN 128
#define BK 32
#define LDT 32   // LDS tile row stride in bf16 elems (contiguous for async cp)

template<bool C_F32>
__global__ __launch_bounds__(256)
void gemm_bt_bias(const u16* __restrict__ A,
                  const u16* __restrict__ W0, const u16* __restrict__ W1, const u16* __restrict__ W2,
                  const float* __restrict__ B0, const float* __restrict__ B1, const float* __restrict__ B2,
                  void* __restrict__ C0, void* __restrict__ C1, void* __restrict__ C2,
                  float scale0)
{
  const int z = blockIdx.z;
  const u16* W    = (z == 0) ? W0 : (z == 1) ? W1 : W2;
  const float* Bi = (z == 0) ? B0 : (z == 1) ? B1 : B2;
  void* C         = (z == 0) ? C0 : (z == 1) ? C1 : C2;
  const float sc  = (z == 0) ? scale0 : 1.0f;

  const int n0 = blockIdx.x * BN;
  const int m0 = blockIdx.y * BM;
  const int tid  = threadIdx.x;
  const int lane = tid & 63;
  const int wave = tid >> 6;
  const int wm = (wave >> 1) * 64;
  const int wn = (wave & 1) * 64;
  const int quad = lane >> 4;
  const int l16  = lane & 15;

  __shared__ u16 As[BM * LDT];
  __shared__ u16 Bs[BN * LDT];

  floatx4 acc[4][4];
#pragma unroll
  for (int i = 0; i < 4; ++i)
#pragma unroll
    for (int j = 0; j < 4; ++j)
      acc[i][j] = (floatx4){0.f, 0.f, 0.f, 0.f};

  for (int k0 = 0; k0 < ND; k0 += BK) {
#pragma unroll
    for (int it = 0; it < 2; ++it) {
      int idx = tid + it * 256;            // 0..511
      int rr  = idx >> 2;                  // 0..127
      int c8  = (idx & 3) << 3;            // 0,8,16,24
      async_cp16(&Bs[idx * 8], &W[(size_t)(n0 + rr) * ND + k0 + c8]);
      async_cp16(&As[idx * 8], &A[(size_t)(m0 + rr) * ND + k0 + c8]);
    }
    __syncthreads();

    short8 af[4], bfr[4];
#pragma unroll
    for (int i = 0; i < 4; ++i)
      af[i] = *(const short8*)&As[(wm + i * 16 + l16) * LDT + quad * 8];
#pragma unroll
    for (int j = 0; j < 4; ++j)
      bfr[j] = *(const short8*)&Bs[(wn + j * 16 + l16) * LDT + quad * 8];

#pragma unroll
    for (int i = 0; i < 4; ++i)
#pragma unroll
      for (int j = 0; j < 4; ++j)
        acc[i][j] = __builtin_amdgcn_mfma_f32_16x16x32_bf16(af[i], bfr[j], acc[i][j], 0, 0, 0);
    __syncthreads();
  }

  // Epilogue. D map: row=(lane>>4)*4+r, col=lane&15.
#pragma unroll
  for (int j = 0; j < 4; ++j) {
    const int ncol = n0 + wn + j * 16 + l16;
    const float bv = Bi[ncol];
#pragma unroll
    for (int i = 0; i < 4; ++i) {
      const int mbase = m0 + wm + i * 16 + quad * 4;
#pragma unroll
      for (int r2 = 0; r2 < 4; ++r2) {
        float v = (acc[i][j][r2] + bv) * sc;
        if (C_F32) ((float*)C)[(size_t)(mbase + r2) * ND + ncol] = v;
        else       ((u16*)C)[(size_t)(mbase + r2) * ND + ncol] = f2bf(v);
      }
    }
  }
}

// ---------------------------------------------------------------------------
// MFMA flash attention (r5 structure + balanced schedule + DPP P-writes).
// No-max softmax (scores bounded; exp cannot overflow). l via MFMA with ones
// B-fragment. Block = 256 threads (4 waves), one (b,h), 64-row Q tile; wave
// owns 16 rows. K/V staged in LDS per chunk (coalesced, shared by 4 waves).
//
// SCHEDULE: 1D grid of 1024. Linear round-robin dispatch previously gave each
// CU 4 blocks of the SAME qt (256 = 8 full bh columns) -> 2x imbalance (worst
// CU 132 chunks vs 66 balanced). Decode (r=t>>8, s=t&7, bh=(t&255)>>3):
// qt = {31-s, 16+s, 15-s, s}[r]  ->  per-slot sum = 66 chunks for every s.
// Y aliases Q (wave reads its Q rows into regs first, writes same rows last).
// ---------------------------------------------------------------------------
#define KC 64
#define PSTR 72   // padded LDS row stride (bf16)

__global__ __launch_bounds__(256)
void attn_mfma(const u16* __restrict__ Q, const u16* __restrict__ K,
               const u16* __restrict__ V, const int* __restrict__ msk,
               u16* __restrict__ Y)
{
  const int t = blockIdx.x;
  const int r = t >> 8;
  const int s = t & 7;
  const int bh = (t & 255) >> 3;
  const int qt = (r == 0) ? 31 - s : (r == 1) ? 16 + s : (r == 2) ? 15 - s : s;
  const int b = bh >> 4;
  const int h = bh & 15;
  const int q0 = qt * 64;
  const int tid  = threadIdx.x;
  const int lane = tid & 63;
  const int wave = tid >> 6;
  const int wq   = wave * 16;      // wave's q-row offset in tile
  const int quad = lane >> 4;
  const int l16  = lane & 15;

  __shared__ u16 Ks[KC][PSTR];     // [key][dim]
  __shared__ u16 Vt[NDH][PSTR];    // [dim][key]
  __shared__ u16 Ps[64][PSTR];     // [q_local][key]
  __shared__ u16 Ms[NL];           // key-pad multiplier 0/1

  const int nchunks = qt + 1;

  // Stage mask multipliers (causally-reachable prefix only)
  for (int j = tid; j < nchunks * KC; j += 256) Ms[j] = (u16)(msk[b * NL + j] ? 1 : 0);

  // Q fragments (A-layout: m=l16, k=quad*8+j), pre-scaled by 1/8 in GEMM1.
  short8 qf[2];
#pragma unroll
  for (int kk = 0; kk < 2; ++kk)
    qf[kk] = *(const short8*)&Q[(size_t)(b * NL + q0 + wq + l16) * ND
                                + h * NDH + kk * 32 + quad * 8];

  // Constant ones B-fragment: B[n=l16][k] = (n==0) ? 1.0bf : 0
  short8 onesf;
  {
    const short ov = (l16 == 0) ? (short)0x3F80 : (short)0;
#pragma unroll
    for (int e = 0; e < 8; ++e) onesf[e] = ov;
  }

  floatx4 o[4];                    // output accum, un-normalized
#pragma unroll
  for (int ot = 0; ot < 4; ++ot) o[ot] = (floatx4){0.f, 0.f, 0.f, 0.f};
  floatx4 lacc = (floatx4){0.f, 0.f, 0.f, 0.f};   // col 0 holds row-sum l

  const int odd = l16 & 1;
  for (int kc = 0; kc < nchunks; ++kc) {
    const int k0 = kc * KC;

    // ---- stage K (natural, b128) ----
#pragma unroll
    for (int p = 0; p < 2; ++p) {
      int idx = tid + p * 256;       // 0..511
      int rr = idx >> 3, c = (idx & 7) << 3;
      *(uint4*)&Ks[rr][c] = *(const uint4*)&K[(size_t)(b * NL + k0 + rr) * ND + h * NDH + c];
    }
    // ---- stage V transposed (paired rows -> b32 writes) ----
    {
      int rv = (tid & 31) * 2;        // 0,2,...,62
      int c  = (tid >> 5) * 8;        // 0,8,...,56
      uint4 va = *(const uint4*)&V[(size_t)(b * NL + k0 + rv)     * ND + h * NDH + c];
      uint4 vb = *(const uint4*)&V[(size_t)(b * NL + k0 + rv + 1) * ND + h * NDH + c];
      const u16* ap = (const u16*)&va;
      const u16* bp = (const u16*)&vb;
#pragma unroll
      for (int e = 0; e < 8; ++e)
        *(unsigned int*)&Vt[c + e][rv] = (unsigned int)ap[e] | ((unsigned int)bp[e] << 16);
    }
    __syncthreads();

    // ---- S = Q K^T  (C-layout: row=quad*4+r2, col=ct*16+l16) ----
    floatx4 sc[4];
#pragma unroll
    for (int ct = 0; ct < 4; ++ct) {
      short8 kf0 = *(const short8*)&Ks[ct * 16 + l16][quad * 8];
      short8 kf1 = *(const short8*)&Ks[ct * 16 + l16][32 + quad * 8];
      floatx4 a = (floatx4){0.f, 0.f, 0.f, 0.f};
      a = __builtin_amdgcn_mfma_f32_16x16x32_bf16(qf[0], kf0, a, 0, 0, 0);
      a = __builtin_amdgcn_mfma_f32_16x16x32_bf16(qf[1], kf1, a, 0, 0, 0);
      sc[ct] = a;
    }

    // ---- P = pad * causal * exp(S); packed b32 LDS writes (own rows) ----
    const bool diag = (kc == qt);
    const int rowb = q0 + wq + quad * 4;
#pragma unroll
    for (int ct = 0; ct < 4; ++ct) {
      const int col = k0 + ct * 16 + l16;
      const float pmul = (float)Ms[col];
      unsigned bb[4];
#pragma unroll
      for (int r2 = 0; r2 < 4; ++r2) {
        float p = pmul * __expf(sc[ct][r2]);
        if (diag) p = (col > rowb + r2) ? 0.f : p;
        bb[r2] = (unsigned)f2bf(p);
      }
      unsigned n0v = dpp_xor1(bb[0]), n1v = dpp_xor1(bb[1]);
      unsigned n2v = dpp_xor1(bb[2]), n3v = dpp_xor1(bb[3]);
      const int colb  = ct * 16 + (l16 & ~1);
      const int row01 = wq + quad * 4 + odd;
      unsigned d01 = odd ? (n1v | (bb[1] << 16)) : (bb[0] | (n0v << 16));
      unsigned d23 = odd ? (n3v | (bb[3] << 16)) : (bb[2] | (n2v << 16));
      *(unsigned*)&Ps[row01][colb]     = d01;
      *(unsigned*)&Ps[row01 + 2][colb] = d23;
    }

    // ---- O += P V ; l += P * ones ----
#pragma unroll
    for (int kk = 0; kk < 2; ++kk) {
      short8 pf = *(const short8*)&Ps[wq + l16][kk * 32 + quad * 8];
#pragma unroll
      for (int ot = 0; ot < 4; ++ot) {
        short8 vf = *(const short8*)&Vt[ot * 16 + l16][kk * 32 + quad * 8];
        o[ot] = __builtin_amdgcn_mfma_f32_16x16x32_bf16(pf, vf, o[ot], 0, 0, 0);
      }
      lacc = __builtin_amdgcn_mfma_f32_16x16x32_bf16(pf, onesf, lacc, 0, 0, 0);
    }
    __syncthreads();   // protect Ks/Vt before restaging
  }

  // ---- epilogue: O / l -> Y (aliases Q; our rows only, reads done) ----
  float inv[4];
#pragma unroll
  for (int r2 = 0; r2 < 4; ++r2) {
    const float l = __shfl(lacc[r2], quad << 4);   // col 0 of the l-tile
    inv[r2] = 1.0f / l;
  }
#pragma unroll
  for (int ot = 0; ot < 4; ++ot)
#pragma unroll
    for (int r2 = 0; r2 < 4; ++r2) {
      const int row = q0 + wq + quad * 4 + r2;
      Y[(size_t)(b * NL + row) * ND + h * NDH + ot * 16 + l16] = f2bf(o[ot][r2] * inv[r2]);
    }
}

// ---------------------------------------------------------------------------
extern "C" void kernel_launch(void* const* d_in, const int* in_sizes, int n_in,
                              void* d_out, int out_size, void* d_ws, size_t ws_size,
                              hipStream_t stream) {
  const float* x  = (const float*)d_in[0];
  const int*   m  = (const int*)d_in[1];
  const float* Wq = (const float*)d_in[2];
  const float* bq = (const float*)d_in[3];
  const float* Wk = (const float*)d_in[4];
  const float* bk = (const float*)d_in[5];
  const float* Wv = (const float*)d_in[6];
  const float* bv = (const float*)d_in[7];
  const float* Wp = (const float*)d_in[8];
  const float* bp = (const float*)d_in[9];
  float* out = (float*)d_out;

  // Workspace (32 MiB): Q|Y alias (8) + K (8) + V (8) + Wb bf16 x4 (8)
  // xb (bf16 x, 8 MiB) lives in d_out: read only by GEMM1, clobbered only by
  // the final proj GEMM (sequentially after).
  const size_t per = (size_t)NM * ND;
  u16* Qb = (u16*)d_ws;
  u16* Kb = Qb + per;
  u16* Vb = Kb + per;
  u16* Wb = Vb + per;              // 4 * ND*ND bf16, contiguous
  u16* Yb = Qb;                    // alias
  u16* xb = (u16*)d_out;

  // 0) fp32 -> bf16 for weights and x
  cvt_all<<<2048, 256, 0, stream>>>(Wq, Wk, Wv, Wp, x, Wb, xb);

  // 1) QKV projections (all-bf16 async staging; Q pre-scaled by 1/8)
  dim3 gq(ND / BN, NM / BM, 3);
  gemm_bt_bias<false><<<gq, 256, 0, stream>>>(
      xb, Wb, Wb + (size_t)ND * ND, Wb + 2 * (size_t)ND * ND,
      bq, bk, bv, (void*)Qb, (void*)Kb, (void*)Vb, 0.125f);

  // 2) MFMA flash attention, balanced 1D schedule (Y aliases Q)
  attn_mfma<<<1024, 256, 0, stream>>>(Qb, Kb, Vb, m, Yb);

  // 3) Output projection (A=Y bf16, C=fp32 d_out)
  dim3 gp(ND / BN, NM / BM, 1);
  const u16* Wpb = Wb + 3 * (size_t)ND * ND;
  gemm_bt_bias<true><<<gp, 256, 0, stream>>>(
      Yb, Wpb, Wpb, Wpb, bp, bp, bp,
      (void*)out, (void*)out, (void*)out, 1.0f);
}

// Round 9
// 210.263 us; speedup vs baseline: 1.8238x; 1.0260x over previous
//
#include <hip/hip_runtime.h>
#include <hip/hip_bf16.h>

// Problem constants
#define NB 2
#define NL 2048
#define ND 1024
#define NH 16
#define NDH 64
#define NM (NB*NL)   // 4096 rows total

typedef unsigned short u16;
typedef __attribute__((ext_vector_type(8))) short short8;   // 8 bf16 in 4 VGPRs
typedef __attribute__((ext_vector_type(4))) float floatx4;  // MFMA accumulator

// fp32 -> bf16 round-to-nearest-even (bit trick)
__device__ __forceinline__ u16 f2bf(float f) {
  union { float f; unsigned int u; } v; v.f = f;
  unsigned int r = v.u + 0x7FFF + ((v.u >> 16) & 1);
  return (u16)(r >> 16);
}

// async global->LDS 16B (m97 lever). LDS dest is wave-uniform base + lane*16.
__device__ __forceinline__ void async_cp16(u16* lds, const u16* g) {
  __builtin_amdgcn_global_load_lds(
      (const __attribute__((address_space(1))) void*)g,
      (__attribute__((address_space(3))) void*)lds, 16, 0, 0);
}

// lane <-> lane^1 exchange on the VALU (DPP quad_perm [1,0,3,2]) — no LDS pipe
__device__ __forceinline__ unsigned dpp_xor1(unsigned v) {
  return (unsigned)__builtin_amdgcn_mov_dpp((int)v, 0xB1, 0xF, 0xF, true);
}

// ---------------------------------------------------------------------------
// Pre-convert fp32 -> bf16: Wq,Wk,Wv,Wp (1M elems each) -> Wb, x (4M) -> xb.
// ---------------------------------------------------------------------------
__global__ __launch_bounds__(256)
void cvt_all(const float* __restrict__ wq, const float* __restrict__ wk,
             const float* __restrict__ wv, const float* __restrict__ wp,
             const float* __restrict__ x,
             u16* __restrict__ ow, u16* __restrict__ ox)
{
  const int per4 = ND * ND / 4;            // 262144 float4 per weight matrix
  const int tot  = 4 * per4 + NM * ND / 4; // + 1048576 for x
  for (int t = blockIdx.x * 256 + threadIdx.x; t < tot; t += gridDim.x * 256) {
    const float* src; uint2* dst; int off;
    if (t < 4 * per4) {
      int w = t >> 18; off = t & (per4 - 1);
      src = (w == 0) ? wq : (w == 1) ? wk : (w == 2) ? wv : wp;
      dst = (uint2*)(ow + (size_t)w * ND * ND);
    } else {
      off = t - 4 * per4; src = x; dst = (uint2*)ox;
    }
    float4 f = ((const float4*)src)[off];
    u16 h[4] = { f2bf(f.x), f2bf(f.y), f2bf(f.z), f2bf(f.w) };
    dst[off] = *(const uint2*)h;
  }
}

// ---------------------------------------------------------------------------
// Fused QKV GEMM: one dispatch, logical N = 3072 (z = n0>>10 selects W/bias/
// output). C[m][n] = (sum_k A[m][k] W_z[n][k] + bias_z[n]) * (z==0 ? 1/8 : 1).
// 128x128 tile, BK=32, 256 threads (4 waves as 2x2 of 64x64), MFMA 16x16x32.
// ---------------------------------------------------------------------------
#define BM 128
#define BN 128
#define BK 32
#define LDT 32   // LDS tile row stride in bf16 elems (contiguous for async cp)

__global__ __launch_bounds__(256)
void gemm_qkv(const u16* __restrict__ A, const u16* __restrict__ Wb,
              const float* __restrict__ bq, const float* __restrict__ bk,
              const float* __restrict__ bv,
              u16* __restrict__ Qb, u16* __restrict__ Kb, u16* __restrict__ Vb)
{
  const int n0g = blockIdx.x * BN;          // 0..2944
  const int z   = n0g >> 10;
  const int n0  = n0g & 1023;
  const u16* W    = Wb + (size_t)z * ND * ND;
  const float* Bi = (z == 0) ? bq : (z == 1) ? bk : bv;
  u16* C          = (z == 0) ? Qb : (z == 1) ? Kb : Vb;
  const float sc  = (z == 0) ? 0.125f : 1.0f;

  const int m0 = blockIdx.y * BM;
  const int tid  = threadIdx.x;
  const int lane = tid & 63;
  const int wave = tid >> 6;
  const int wm = (wave >> 1) * 64;
  const int wn = (wave & 1) * 64;
  const int quad = lane >> 4;
  const int l16  = lane & 15;

  __shared__ u16 As[BM * LDT];
  __shared__ u16 Bs[BN * LDT];

  floatx4 acc[4][4];
#pragma unroll
  for (int i = 0; i < 4; ++i)
#pragma unroll
    for (int j = 0; j < 4; ++j)
      acc[i][j] = (floatx4){0.f, 0.f, 0.f, 0.f};

  for (int k0 = 0; k0 < ND; k0 += BK) {
#pragma unroll
    for (int it = 0; it < 2; ++it) {
      int idx = tid + it * 256;            // 0..511
      int rr  = idx >> 2;                  // 0..127
      int c8  = (idx & 3) << 3;            // 0,8,16,24
      async_cp16(&Bs[idx * 8], &W[(size_t)(n0 + rr) * ND + k0 + c8]);
      async_cp16(&As[idx * 8], &A[(size_t)(m0 + rr) * ND + k0 + c8]);
    }
    __syncthreads();

    short8 af[4], bfr[4];
#pragma unroll
    for (int i = 0; i < 4; ++i)
      af[i] = *(const short8*)&As[(wm + i * 16 + l16) * LDT + quad * 8];
#pragma unroll
    for (int j = 0; j < 4; ++j)
      bfr[j] = *(const short8*)&Bs[(wn + j * 16 + l16) * LDT + quad * 8];

#pragma unroll
    for (int i = 0; i < 4; ++i)
#pragma unroll
      for (int j = 0; j < 4; ++j)
        acc[i][j] = __builtin_amdgcn_mfma_f32_16x16x32_bf16(af[i], bfr[j], acc[i][j], 0, 0, 0);
    __syncthreads();
  }

  // Epilogue. D map: row=(lane>>4)*4+r, col=lane&15.
#pragma unroll
  for (int j = 0; j < 4; ++j) {
    const int ncol = n0 + wn + j * 16 + l16;
    const float bv2 = Bi[ncol];
#pragma unroll
    for (int i = 0; i < 4; ++i) {
      const int mbase = m0 + wm + i * 16 + quad * 4;
#pragma unroll
      for (int r2 = 0; r2 < 4; ++r2) {
        float v = (acc[i][j][r2] + bv2) * sc;
        C[(size_t)(mbase + r2) * ND + ncol] = f2bf(v);
      }
    }
  }
}

// ---------------------------------------------------------------------------
// Output projection GEMM: C fp32 = A(bf16) W^T + bias. BN=64 -> 512 blocks
// (2/CU instead of 1/CU: this GEMM is latency-bound, more blocks hide it).
// 4 waves as 2x2 over (64 rows, 32 cols) each: af[4], bf[2], 8 MFMA/iter.
// ---------------------------------------------------------------------------
#define BN2 64

__global__ __launch_bounds__(256)
void gemm_proj(const u16* __restrict__ A, const u16* __restrict__ W,
               const float* __restrict__ Bi, float* __restrict__ C)
{
  const int n0 = blockIdx.x * BN2;
  const int m0 = blockIdx.y * BM;
  const int tid  = threadIdx.x;
  const int lane = tid & 63;
  const int wave = tid >> 6;
  const int wm = (wave >> 1) * 64;
  const int wn = (wave & 1) * 32;
  const int quad = lane >> 4;
  const int l16  = lane & 15;

  __shared__ u16 As[BM * LDT];
  __shared__ u16 Bs[BN2 * LDT];

  floatx4 acc[4][2];
#pragma unroll
  for (int i = 0; i < 4; ++i)
#pragma unroll
    for (int j = 0; j < 2; ++j)
      acc[i][j] = (floatx4){0.f, 0.f, 0.f, 0.f};

  for (int k0 = 0; k0 < ND; k0 += BK) {
#pragma unroll
    for (int it = 0; it < 2; ++it) {
      int idx = tid + it * 256;            // 0..511
      int rr  = idx >> 2;
      int c8  = (idx & 3) << 3;
      async_cp16(&As[idx * 8], &A[(size_t)(m0 + rr) * ND + k0 + c8]);
    }
    {
      int rr = tid >> 2, c8 = (tid & 3) << 3;   // 256 chunks
      async_cp16(&Bs[tid * 8], &W[(size_t)(n0 + rr) * ND + k0 + c8]);
    }
    __syncthreads();

    short8 af[4], bfr[2];
#pragma unroll
    for (int i = 0; i < 4; ++i)
      af[i] = *(const short8*)&As[(wm + i * 16 + l16) * LDT + quad * 8];
#pragma unroll
    for (int j = 0; j < 2; ++j)
      bfr[j] = *(const short8*)&Bs[(wn + j * 16 + l16) * LDT + quad * 8];

#pragma unroll
    for (int i = 0; i < 4; ++i)
#pragma unroll
      for (int j = 0; j < 2; ++j)
        acc[i][j] = __builtin_amdgcn_mfma_f32_16x16x32_bf16(af[i], bfr[j], acc[i][j], 0, 0, 0);
    __syncthreads();
  }

#pragma unroll
  for (int j = 0; j < 2; ++j) {
    const int ncol = n0 + wn + j * 16 + l16;
    const float bv2 = Bi[ncol];
#pragma unroll
    for (int i = 0; i < 4; ++i) {
      const int mbase = m0 + wm + i * 16 + quad * 4;
#pragma unroll
      for (int r2 = 0; r2 < 4; ++r2)
        C[(size_t)(mbase + r2) * ND + ncol] = acc[i][j][r2] + bv2;
    }
  }
}

// ---------------------------------------------------------------------------
// MFMA flash attention (r8 structure + XCD-aware schedule).
// No-max softmax; l via MFMA ones-column; DPP-packed b32 P-writes.
// Block = 256 threads (4 waves), one (b,h), 64-row Q tile; wave owns 16 rows.
//
// SCHEDULE (1024 blocks): t -> xcd = t&7 (blocks round-robin XCDs),
// r = t>>8 (residency round), v = (t>>3)&31.
//   bh = xcd*4 + r   -> each XCD touches only 4 heads: K/V/Q footprint 3 MB
//                       <= 4 MB per-XCD L2 (r8 had all 32 heads -> 24 MB
//                       thrash -> 62.6 MB FETCH vs 24.7 ideal).
//   qt = {v, 31-v, (v+16)%32, (15-v)%32}[r] -> bijective over (bh,qt); every
//   CU's 4 rounds sum to exactly 66 chunks (balance preserved).
// Y aliases Q (wave reads its Q rows into regs first, writes same rows last).
// ---------------------------------------------------------------------------
#define KC 64
#define PSTR 72   // padded LDS row stride (bf16)

__global__ __launch_bounds__(256)
void attn_mfma(const u16* __restrict__ Q, const u16* __restrict__ K,
               const u16* __restrict__ V, const int* __restrict__ msk,
               u16* __restrict__ Y)
{
  const int t = blockIdx.x;
  const int r = t >> 8;            // 0..3
  const int xcd = t & 7;
  const int v = (t >> 3) & 31;
  const int bh = xcd * 4 + r;
  const int qt = (r == 0) ? v
               : (r == 1) ? 31 - v
               : (r == 2) ? ((v + 16) & 31)
                          : ((15 - v) & 31);
  const int b = bh >> 4;
  const int h = bh & 15;
  const int q0 = qt * 64;
  const int tid  = threadIdx.x;
  const int lane = tid & 63;
  const int wave = tid >> 6;
  const int wq   = wave * 16;      // wave's q-row offset in tile
  const int quad = lane >> 4;
  const int l16  = lane & 15;

  __shared__ u16 Ks[KC][PSTR];     // [key][dim]
  __shared__ u16 Vt[NDH][PSTR];    // [dim][key]
  __shared__ u16 Ps[64][PSTR];     // [q_local][key]
  __shared__ u16 Ms[NL];           // key-pad multiplier 0/1

  const int nchunks = qt + 1;

  // Stage mask multipliers (causally-reachable prefix only)
  for (int j = tid; j < nchunks * KC; j += 256) Ms[j] = (u16)(msk[b * NL + j] ? 1 : 0);

  // Q fragments (A-layout: m=l16, k=quad*8+j), pre-scaled by 1/8 in GEMM1.
  short8 qf[2];
#pragma unroll
  for (int kk = 0; kk < 2; ++kk)
    qf[kk] = *(const short8*)&Q[(size_t)(b * NL + q0 + wq + l16) * ND
                                + h * NDH + kk * 32 + quad * 8];

  // Constant ones B-fragment: B[n=l16][k] = (n==0) ? 1.0bf : 0
  short8 onesf;
  {
    const short ov = (l16 == 0) ? (short)0x3F80 : (short)0;
#pragma unroll
    for (int e = 0; e < 8; ++e) onesf[e] = ov;
  }

  floatx4 o[4];                    // output accum, un-normalized
#pragma unroll
  for (int ot = 0; ot < 4; ++ot) o[ot] = (floatx4){0.f, 0.f, 0.f, 0.f};
  floatx4 lacc = (floatx4){0.f, 0.f, 0.f, 0.f};   // col 0 holds row-sum l

  const int odd = l16 & 1;
  for (int kc = 0; kc < nchunks; ++kc) {
    const int k0 = kc * KC;

    // ---- stage K (natural, b128) ----
#pragma unroll
    for (int p = 0; p < 2; ++p) {
      int idx = tid + p * 256;       // 0..511
      int rr = idx >> 3, c = (idx & 7) << 3;
      *(uint4*)&Ks[rr][c] = *(const uint4*)&K[(size_t)(b * NL + k0 + rr) * ND + h * NDH + c];
    }
    // ---- stage V transposed (paired rows -> b32 writes) ----
    {
      int rv = (tid & 31) * 2;        // 0,2,...,62
      int c  = (tid >> 5) * 8;        // 0,8,...,56
      uint4 va = *(const uint4*)&V[(size_t)(b * NL + k0 + rv)     * ND + h * NDH + c];
      uint4 vb = *(const uint4*)&V[(size_t)(b * NL + k0 + rv + 1) * ND + h * NDH + c];
      const u16* ap = (const u16*)&va;
      const u16* bp = (const u16*)&vb;
#pragma unroll
      for (int e = 0; e < 8; ++e)
        *(unsigned int*)&Vt[c + e][rv] = (unsigned int)ap[e] | ((unsigned int)bp[e] << 16);
    }
    __syncthreads();

    // ---- S = Q K^T  (C-layout: row=quad*4+r2, col=ct*16+l16) ----
    floatx4 sc[4];
#pragma unroll
    for (int ct = 0; ct < 4; ++ct) {
      short8 kf0 = *(const short8*)&Ks[ct * 16 + l16][quad * 8];
      short8 kf1 = *(const short8*)&Ks[ct * 16 + l16][32 + quad * 8];
      floatx4 a = (floatx4){0.f, 0.f, 0.f, 0.f};
      a = __builtin_amdgcn_mfma_f32_16x16x32_bf16(qf[0], kf0, a, 0, 0, 0);
      a = __builtin_amdgcn_mfma_f32_16x16x32_bf16(qf[1], kf1, a, 0, 0, 0);
      sc[ct] = a;
    }

    // ---- P = pad * causal * exp(S); packed b32 LDS writes (own rows) ----
    const bool diag = (kc == qt);
    const int rowb = q0 + wq + quad * 4;
#pragma unroll
    for (int ct = 0; ct < 4; ++ct) {
      const int col = k0 + ct * 16 + l16;
      const float pmul = (float)Ms[col];
      unsigned bb[4];
#pragma unroll
      for (int r2 = 0; r2 < 4; ++r2) {
        float p = pmul * __expf(sc[ct][r2]);
        if (diag) p = (col > rowb + r2) ? 0.f : p;
        bb[r2] = (unsigned)f2bf(p);
      }
      unsigned n0v = dpp_xor1(bb[0]), n1v = dpp_xor1(bb[1]);
      unsigned n2v = dpp_xor1(bb[2]), n3v = dpp_xor1(bb[3]);
      const int colb  = ct * 16 + (l16 & ~1);
      const int row01 = wq + quad * 4 + odd;
      unsigned d01 = odd ? (n1v | (bb[1] << 16)) : (bb[0] | (n0v << 16));
      unsigned d23 = odd ? (n3v | (bb[3] << 16)) : (bb[2] | (n2v << 16));
      *(unsigned*)&Ps[row01][colb]     = d01;
      *(unsigned*)&Ps[row01 + 2][colb] = d23;
    }

    // ---- O += P V ; l += P * ones ----
#pragma unroll
    for (int kk = 0; kk < 2; ++kk) {
      short8 pf = *(const short8*)&Ps[wq + l16][kk * 32 + quad * 8];
#pragma unroll
      for (int ot = 0; ot < 4; ++ot) {
        short8 vf = *(const short8*)&Vt[ot * 16 + l16][kk * 32 + quad * 8];
        o[ot] = __builtin_amdgcn_mfma_f32_16x16x32_bf16(pf, vf, o[ot], 0, 0, 0);
      }
      lacc = __builtin_amdgcn_mfma_f32_16x16x32_bf16(pf, onesf, lacc, 0, 0, 0);
    }
    __syncthreads();   // protect Ks/Vt before restaging
  }

  // ---- epilogue: O / l -> Y (aliases Q; our rows only, reads done) ----
  float inv[4];
#pragma unroll
  for (int r2 = 0; r2 < 4; ++r2) {
    const float l = __shfl(lacc[r2], quad << 4);   // col 0 of the l-tile
    inv[r2] = 1.0f / l;
  }
#pragma unroll
  for (int ot = 0; ot < 4; ++ot)
#pragma unroll
    for (int r2 = 0; r2 < 4; ++r2) {
      const int row = q0 + wq + quad * 4 + r2;
      Y[(size_t)(b * NL + row) * ND + h * NDH + ot * 16 + l16] = f2bf(o[ot][r2] * inv[r2]);
    }
}

// ---------------------------------------------------------------------------
extern "C" void kernel_launch(void* const* d_in, const int* in_sizes, int n_in,
                              void* d_out, int out_size, void* d_ws, size_t ws_size,
                              hipStream_t stream) {
  const float* x  = (const float*)d_in[0];
  const int*   m  = (const int*)d_in[1];
  const float* Wq = (const float*)d_in[2];
  const float* bq = (const float*)d_in[3];
  const float* Wk = (const float*)d_in[4];
  const float* bk = (const float*)d_in[5];
  const float* Wv = (const float*)d_in[6];
  const float* bv = (const float*)d_in[7];
  const float* Wp = (const float*)d_in[8];
  const float* bp = (const float*)d_in[9];
  float* out = (float*)d_out;

  // Workspace (32 MiB): Q|Y alias (8) + K (8) + V (8) + Wb bf16 x4 (8)
  // xb (bf16 x, 8 MiB) lives in d_out: read only by gemm_qkv, clobbered only
  // by the final proj GEMM (sequentially after).
  const size_t per = (size_t)NM * ND;
  u16* Qb = (u16*)d_ws;
  u16* Kb = Qb + per;
  u16* Vb = Kb + per;
  u16* Wb = Vb + per;              // 4 * ND*ND bf16, contiguous
  u16* Yb = Qb;                    // alias
  u16* xb = (u16*)d_out;

  // 0) fp32 -> bf16 for weights and x
  cvt_all<<<2048, 256, 0, stream>>>(Wq, Wk, Wv, Wp, x, Wb, xb);

  // 1) QKV projections, single fused dispatch (Q pre-scaled by 1/8)
  gemm_qkv<<<dim3(3 * ND / BN, NM / BM), 256, 0, stream>>>(
      xb, Wb, bq, bk, bv, Qb, Kb, Vb);

  // 2) MFMA flash attention, XCD-aware balanced schedule (Y aliases Q)
  attn_mfma<<<1024, 256, 0, stream>>>(Qb, Kb, Vb, m, Yb);

  // 3) Output projection (BN=64: 512 blocks, 2/CU)
  const u16* Wpb = Wb + 3 * (size_t)ND * ND;
  gemm_proj<<<dim3(ND / BN2, NM / BM), 256, 0, stream>>>(Yb, Wpb, bp, out);
}

// Round 11
// 195.479 us; speedup vs baseline: 1.9617x; 1.0756x over previous
//
#include <hip/hip_runtime.h>
#include <hip/hip_bf16.h>

// Problem constants
#define NB 2
#define NL 2048
#define ND 1024
#define NH 16
#define NDH 64
#define NM (NB*NL)   // 4096 rows total

typedef unsigned short u16;
typedef __attribute__((ext_vector_type(8))) short short8;   // 8 bf16 in 4 VGPRs
typedef __attribute__((ext_vector_type(4))) float floatx4;  // MFMA accumulator

#define QSCALE 0.180336880f   // 0.125 * log2(e): lets attention use exp2

// fp32 -> bf16 round-to-nearest-even (bit trick)
__device__ __forceinline__ u16 f2bf(float f) {
  union { float f; unsigned int u; } v; v.f = f;
  unsigned int r = v.u + 0x7FFF + ((v.u >> 16) & 1);
  return (u16)(r >> 16);
}

// async global->LDS 16B (m97 lever). LDS dest is wave-uniform base + lane*16.
__device__ __forceinline__ void async_cp16(const u16* lds, const u16* g) {
  __builtin_amdgcn_global_load_lds(
      (const __attribute__((address_space(1))) void*)g,
      (__attribute__((address_space(3))) void*)lds, 16, 0, 0);
}

// lane <-> lane^1 exchange on the VALU (DPP quad_perm [1,0,3,2]) — no LDS pipe
__device__ __forceinline__ float dpp_xor1_f(float v) {
  return __int_as_float(__builtin_amdgcn_mov_dpp(__float_as_int(v), 0xB1, 0xF, 0xF, true));
}

// pack two fp32 -> bf16x2 dword (HW pk-cvt where available)
__device__ __forceinline__ unsigned pk_bf16(float lo, float hi) {
  __hip_bfloat162 h2 = __float22bfloat162_rn(make_float2(lo, hi));
  return *(unsigned*)&h2;
}

// ---------------------------------------------------------------------------
// Pre-convert fp32 -> bf16: Wq,Wk,Wv,Wp (1M elems each) -> Wb, x (4M) -> xb.
// ---------------------------------------------------------------------------
__global__ __launch_bounds__(256)
void cvt_all(const float* __restrict__ wq, const float* __restrict__ wk,
             const float* __restrict__ wv, const float* __restrict__ wp,
             const float* __restrict__ x,
             u16* __restrict__ ow, u16* __restrict__ ox)
{
  const int per4 = ND * ND / 4;            // 262144 float4 per weight matrix
  const int tot  = 4 * per4 + NM * ND / 4; // + 1048576 for x
  for (int t = blockIdx.x * 256 + threadIdx.x; t < tot; t += gridDim.x * 256) {
    const float* src; uint2* dst; int off;
    if (t < 4 * per4) {
      int w = t >> 18; off = t & (per4 - 1);
      src = (w == 0) ? wq : (w == 1) ? wk : (w == 2) ? wv : wp;
      dst = (uint2*)(ow + (size_t)w * ND * ND);
    } else {
      off = t - 4 * per4; src = x; dst = (uint2*)ox;
    }
    float4 f = ((const float4*)src)[off];
    u16 h[4] = { f2bf(f.x), f2bf(f.y), f2bf(f.z), f2bf(f.w) };
    dst[off] = *(const uint2*)h;
  }
}

// ---------------------------------------------------------------------------
// Fused QKV GEMM: one dispatch, logical N = 3072 (z = n0>>10 selects W/bias/
// output). Q output pre-scaled by QSCALE (score scale folded + exp2 base).
// 128x128 tile, BK=32, 256 threads (4 waves as 2x2 of 64x64), MFMA 16x16x32.
// ---------------------------------------------------------------------------
#define BM 128
#define BN 128
#define BK 32
#define LDT 32   // LDS tile row stride in bf16 elems (contiguous for async cp)

__global__ __launch_bounds__(256)
void gemm_qkv(const u16* __restrict__ A, const u16* __restrict__ Wb,
              const float* __restrict__ bq, const float* __restrict__ bk,
              const float* __restrict__ bv,
              u16* __restrict__ Qb, u16* __restrict__ Kb, u16* __restrict__ Vb)
{
  const int n0g = blockIdx.x * BN;          // 0..2944
  const int z   = n0g >> 10;
  const int n0  = n0g & 1023;
  const u16* W    = Wb + (size_t)z * ND * ND;
  const float* Bi = (z == 0) ? bq : (z == 1) ? bk : bv;
  u16* C          = (z == 0) ? Qb : (z == 1) ? Kb : Vb;
  const float sc  = (z == 0) ? QSCALE : 1.0f;

  const int m0 = blockIdx.y * BM;
  const int tid  = threadIdx.x;
  const int lane = tid & 63;
  const int wave = tid >> 6;
  const int wm = (wave >> 1) * 64;
  const int wn = (wave & 1) * 64;
  const int quad = lane >> 4;
  const int l16  = lane & 15;

  __shared__ u16 As[BM * LDT];
  __shared__ u16 Bs[BN * LDT];

  floatx4 acc[4][4];
#pragma unroll
  for (int i = 0; i < 4; ++i)
#pragma unroll
    for (int j = 0; j < 4; ++j)
      acc[i][j] = (floatx4){0.f, 0.f, 0.f, 0.f};

  for (int k0 = 0; k0 < ND; k0 += BK) {
#pragma unroll
    for (int it = 0; it < 2; ++it) {
      int idx = tid + it * 256;            // 0..511
      int rr  = idx >> 2;                  // 0..127
      int c8  = (idx & 3) << 3;            // 0,8,16,24
      async_cp16(&Bs[idx * 8], &W[(size_t)(n0 + rr) * ND + k0 + c8]);
      async_cp16(&As[idx * 8], &A[(size_t)(m0 + rr) * ND + k0 + c8]);
    }
    __syncthreads();

    short8 af[4], bfr[4];
#pragma unroll
    for (int i = 0; i < 4; ++i)
      af[i] = *(const short8*)&As[(wm + i * 16 + l16) * LDT + quad * 8];
#pragma unroll
    for (int j = 0; j < 4; ++j)
      bfr[j] = *(const short8*)&Bs[(wn + j * 16 + l16) * LDT + quad * 8];

#pragma unroll
    for (int i = 0; i < 4; ++i)
#pragma unroll
      for (int j = 0; j < 4; ++j)
        acc[i][j] = __builtin_amdgcn_mfma_f32_16x16x32_bf16(af[i], bfr[j], acc[i][j], 0, 0, 0);
    __syncthreads();
  }

  // Epilogue. D map: row=(lane>>4)*4+r, col=lane&15.
#pragma unroll
  for (int j = 0; j < 4; ++j) {
    const int ncol = n0 + wn + j * 16 + l16;
    const float bv2 = Bi[ncol];
#pragma unroll
    for (int i = 0; i < 4; ++i) {
      const int mbase = m0 + wm + i * 16 + quad * 4;
#pragma unroll
      for (int r2 = 0; r2 < 4; ++r2) {
        float v = (acc[i][j][r2] + bv2) * sc;
        C[(size_t)(mbase + r2) * ND + ncol] = f2bf(v);
      }
    }
  }
}

// ---------------------------------------------------------------------------
// Output projection GEMM: C fp32 = A(bf16) W^T + bias. BN=64 -> 512 blocks.
// ---------------------------------------------------------------------------
#define BN2 64

__global__ __launch_bounds__(256)
void gemm_proj(const u16* __restrict__ A, const u16* __restrict__ W,
               const float* __restrict__ Bi, float* __restrict__ C)
{
  const int n0 = blockIdx.x * BN2;
  const int m0 = blockIdx.y * BM;
  const int tid  = threadIdx.x;
  const int lane = tid & 63;
  const int wave = tid >> 6;
  const int wm = (wave >> 1) * 64;
  const int wn = (wave & 1) * 32;
  const int quad = lane >> 4;
  const int l16  = lane & 15;

  __shared__ u16 As[BM * LDT];
  __shared__ u16 Bs[BN2 * LDT];

  floatx4 acc[4][2];
#pragma unroll
  for (int i = 0; i < 4; ++i)
#pragma unroll
    for (int j = 0; j < 2; ++j)
      acc[i][j] = (floatx4){0.f, 0.f, 0.f, 0.f};

  for (int k0 = 0; k0 < ND; k0 += BK) {
#pragma unroll
    for (int it = 0; it < 2; ++it) {
      int idx = tid + it * 256;            // 0..511
      int rr  = idx >> 2;
      int c8  = (idx & 3) << 3;
      async_cp16(&As[idx * 8], &A[(size_t)(m0 + rr) * ND + k0 + c8]);
    }
    {
      int rr = tid >> 2, c8 = (tid & 3) << 3;   // 256 chunks
      async_cp16(&Bs[tid * 8], &W[(size_t)(n0 + rr) * ND + k0 + c8]);
    }
    __syncthreads();

    short8 af[4], bfr[2];
#pragma unroll
    for (int i = 0; i < 4; ++i)
      af[i] = *(const short8*)&As[(wm + i * 16 + l16) * LDT + quad * 8];
#pragma unroll
    for (int j = 0; j < 2; ++j)
      bfr[j] = *(const short8*)&Bs[(wn + j * 16 + l16) * LDT + quad * 8];

#pragma unroll
    for (int i = 0; i < 4; ++i)
#pragma unroll
      for (int j = 0; j < 2; ++j)
        acc[i][j] = __builtin_amdgcn_mfma_f32_16x16x32_bf16(af[i], bfr[j], acc[i][j], 0, 0, 0);
    __syncthreads();
  }

#pragma unroll
  for (int j = 0; j < 2; ++j) {
    const int ncol = n0 + wn + j * 16 + l16;
    const float bv2 = Bi[ncol];
#pragma unroll
    for (int i = 0; i < 4; ++i) {
      const int mbase = m0 + wm + i * 16 + quad * 4;
#pragma unroll
      for (int r2 = 0; r2 < 4; ++r2)
        C[(size_t)(mbase + r2) * ND + ncol] = acc[i][j][r2] + bv2;
    }
  }
}

// ---------------------------------------------------------------------------
// V transpose: V [B,L,H,DH] bf16 -> VT [B,H,DH,L] bf16. 64x64 tiles via LDS.
// (verified r7) — enables zero-VALU async VT staging in attention.
// ---------------------------------------------------------------------------
#define TSTR 66
__global__ __launch_bounds__(256)
void vtrans(const u16* __restrict__ V, u16* __restrict__ VT)
{
  const int lt = blockIdx.x;        // l tile 0..31
  const int bh = blockIdx.y;
  const int b = bh >> 4, h = bh & 15;
  const int l0 = lt * 64;
  const int tid = threadIdx.x;
  __shared__ u16 Ls[64][TSTR];
#pragma unroll
  for (int p = 0; p < 2; ++p) {
    int idx = tid + p * 256;
    int r = idx >> 3, c = (idx & 7) << 3;
    *(uint4*)&Ls[r][c] = *(const uint4*)&V[(size_t)(b * NL + l0 + r) * ND + h * NDH + c];
  }
  __syncthreads();
#pragma unroll
  for (int p = 0; p < 2; ++p) {
    int idx = tid + p * 256;
    int lg = idx & 7, d = idx >> 3;   // lg = l-subgroup, d = dim 0..63
    u16 tb[8];
#pragma unroll
    for (int e = 0; e < 8; ++e) tb[e] = Ls[lg * 8 + e][d];
    *(uint4*)&VT[((size_t)(b * NH + h) * NDH + d) * NL + l0 + lg * 8] = *(const uint4*)tb;
  }
}

// ---------------------------------------------------------------------------
// MFMA flash attention (r9 + VALU diet).
//  - no-max softmax via exp2 (Q pre-scaled by 0.125*log2e in gemm_qkv);
//    __builtin_amdgcn_exp2f = single v_exp_f32.
//  - K and VT tiles staged by async_cp16 with xor-chunk swizzle:
//    16B chunk ch of row r lands in LDS slot ch^(r&7) -> frag reads alias
//    only 2-way on banks (free, m136) despite unpadded 128B row stride.
//  - P packed to LDS via float-DPP pair exchange + HW pk bf16 cvt.
//  - l via MFMA ones-column. Y aliases Q.
// SCHEDULE (1024 blocks): xcd=t&7, r=t>>8, v=(t>>3)&31; bh=xcd*4+r (4 heads
// per XCD -> L2-resident K/V); qt={v,31-v,(v+16)%32,(15-v)%32}[r] (balanced).
// ---------------------------------------------------------------------------
#define KC 64
#define PSTR 72   // padded LDS row stride for Ps (bf16)

__global__ __launch_bounds__(256)
void attn_mfma(const u16* __restrict__ Q, const u16* __restrict__ K,
               const u16* __restrict__ VT, const int* __restrict__ msk,
               u16* __restrict__ Y)
{
  const int t = blockIdx.x;
  const int r = t >> 8;            // 0..3
  const int xcd = t & 7;
  const int v = (t >> 3) & 31;
  const int bh = xcd * 4 + r;
  const int qt = (r == 0) ? v
               : (r == 1) ? 31 - v
               : (r == 2) ? ((v + 16) & 31)
                          : ((15 - v) & 31);
  const int b = bh >> 4;
  const int h = bh & 15;
  const int q0 = qt * 64;
  const int tid  = threadIdx.x;
  const int lane = tid & 63;
  const int wave = tid >> 6;
  const int wq   = wave * 16;      // wave's q-row offset in tile
  const int quad = lane >> 4;
  const int l16  = lane & 15;

  __shared__ u16 Ks[KC * 64];      // [key][dim], chunk-swizzled, unpadded
  __shared__ u16 Vt[NDH * 64];     // [dim][key], chunk-swizzled, unpadded
  __shared__ u16 Ps[64][PSTR];     // [q_local][key]
  __shared__ u16 Ms[NL];           // key-pad multiplier 0/1

  const int nchunks = qt + 1;

  // Stage mask multipliers (causally-reachable prefix only)
  for (int j = tid; j < nchunks * KC; j += 256) Ms[j] = (u16)(msk[b * NL + j] ? 1 : 0);

  const u16* Kbase  = K  + (size_t)b * NL * ND + h * NDH;
  const u16* VTbase = VT + (size_t)(b * NH + h) * NDH * NL;

  // Q fragments (A-layout: m=l16, k=quad*8+j), pre-scaled in GEMM1.
  short8 qf[2];
#pragma unroll
  for (int kk = 0; kk < 2; ++kk)
    qf[kk] = *(const short8*)&Q[(size_t)(b * NL + q0 + wq + l16) * ND
                                + h * NDH + kk * 32 + quad * 8];

  // Constant ones B-fragment: B[n=l16][k] = (n==0) ? 1.0bf : 0
  short8 onesf;
  {
    const short ov = (l16 == 0) ? (short)0x3F80 : (short)0;
#pragma unroll
    for (int e = 0; e < 8; ++e) onesf[e] = ov;
  }

  floatx4 o[4];                    // output accum, un-normalized
#pragma unroll
  for (int ot = 0; ot < 4; ++ot) o[ot] = (floatx4){0.f, 0.f, 0.f, 0.f};
  floatx4 lacc = (floatx4){0.f, 0.f, 0.f, 0.f};   // col 0 holds row-sum l

  const int odd = l16 & 1;
  const int sw  = l16 & 7;         // frag-read swizzle key (row & 7)

  for (int kc = 0; kc < nchunks; ++kc) {
    const int k0 = kc * KC;

    // ---- stage K + VT via async, chunk-swizzled (zero VALU pack) ----
#pragma unroll
    for (int p = 0; p < 2; ++p) {
      int sl = tid + p * 256;        // LDS 16B-slot index 0..511
      int rr = sl >> 3;              // row (key for K, dim for VT)
      int ch = (sl & 7) ^ (rr & 7);  // which global chunk goes to this slot
      async_cp16(&Ks[sl * 8], Kbase + (size_t)(k0 + rr) * ND + ch * 8);
      async_cp16(&Vt[sl * 8], VTbase + (size_t)rr * NL + k0 + ch * 8);
    }
    __syncthreads();

    // ---- S = Q K^T  (C-layout: row=quad*4+r2, col=ct*16+l16) ----
    floatx4 sc[4];
#pragma unroll
    for (int ct = 0; ct < 4; ++ct) {
      const u16* krow = &Ks[(ct * 16 + l16) * 64];
      short8 kf0 = *(const short8*)(krow + ((quad ^ sw) << 3));
      short8 kf1 = *(const short8*)(krow + (((4 | quad) ^ sw) << 3));
      floatx4 a = (floatx4){0.f, 0.f, 0.f, 0.f};
      a = __builtin_amdgcn_mfma_f32_16x16x32_bf16(qf[0], kf0, a, 0, 0, 0);
      a = __builtin_amdgcn_mfma_f32_16x16x32_bf16(qf[1], kf1, a, 0, 0, 0);
      sc[ct] = a;
    }

    // ---- P = pad * causal * exp2(S); DPP-pair + pk-cvt b32 LDS writes ----
    const bool diag = (kc == qt);
    const int rowb = q0 + wq + quad * 4;
#pragma unroll
    for (int ct = 0; ct < 4; ++ct) {
      const int col = k0 + ct * 16 + l16;
      const float pmul = (float)Ms[col];
      float pv[4];
#pragma unroll
      for (int r2 = 0; r2 < 4; ++r2) {
        float p = pmul * __builtin_amdgcn_exp2f(sc[ct][r2]);
        if (diag) p = (col > rowb + r2) ? 0.f : p;
        pv[r2] = p;
      }
      float nb0 = dpp_xor1_f(pv[0]), nb1 = dpp_xor1_f(pv[1]);
      float nb2 = dpp_xor1_f(pv[2]), nb3 = dpp_xor1_f(pv[3]);
      const int colb  = ct * 16 + (l16 & ~1);
      const int row01 = wq + quad * 4 + odd;
      unsigned d01 = odd ? pk_bf16(nb1, pv[1]) : pk_bf16(pv[0], nb0);
      unsigned d23 = odd ? pk_bf16(nb3, pv[3]) : pk_bf16(pv[2], nb2);
      *(unsigned*)&Ps[row01][colb]     = d01;
      *(unsigned*)&Ps[row01 + 2][colb] = d23;
    }

    // ---- O += P V ; l += P * ones ----
#pragma unroll
    for (int kk = 0; kk < 2; ++kk) {
      short8 pf = *(const short8*)&Ps[wq + l16][kk * 32 + quad * 8];
#pragma unroll
      for (int ot = 0; ot < 4; ++ot) {
        const u16* vrow = &Vt[(ot * 16 + l16) * 64];
        short8 vf = *(const short8*)(vrow + ((((kk << 2) | quad) ^ sw) << 3));
        o[ot] = __builtin_amdgcn_mfma_f32_16x16x32_bf16(pf, vf, o[ot], 0, 0, 0);
      }
      lacc = __builtin_amdgcn_mfma_f32_16x16x32_bf16(pf, onesf, lacc, 0, 0, 0);
    }
    __syncthreads();   // protect Ks/Vt before restaging
  }

  // ---- epilogue: O / l -> Y (aliases Q; our rows only, reads done) ----
  float inv[4];
#pragma unroll
  for (int r2 = 0; r2 < 4; ++r2) {
    const float l = __shfl(lacc[r2], quad << 4);   // col 0 of the l-tile
    inv[r2] = 1.0f / l;
  }
#pragma unroll
  for (int ot = 0; ot < 4; ++ot)
#pragma unroll
    for (int r2 = 0; r2 < 4; ++r2) {
      const int row = q0 + wq + quad * 4 + r2;
      Y[(size_t)(b * NL + row) * ND + h * NDH + ot * 16 + l16] = f2bf(o[ot][r2] * inv[r2]);
    }
}

// ---------------------------------------------------------------------------
extern "C" void kernel_launch(void* const* d_in, const int* in_sizes, int n_in,
                              void* d_out, int out_size, void* d_ws, size_t ws_size,
                              hipStream_t stream) {
  const float* x  = (const float*)d_in[0];
  const int*   m  = (const int*)d_in[1];
  const float* Wq = (const float*)d_in[2];
  const float* bq = (const float*)d_in[3];
  const float* Wk = (const float*)d_in[4];
  const float* bk = (const float*)d_in[5];
  const float* Wv = (const float*)d_in[6];
  const float* bv = (const float*)d_in[7];
  const float* Wp = (const float*)d_in[8];
  const float* bp = (const float*)d_in[9];
  float* out = (float*)d_out;

  // Workspace (32 MiB): Q|Y alias (8) + K (8) + V (8) + Wb bf16 x4 (8)
  // d_out (16 MiB fp32) moonlights: xb (bf16 x, first 8 MiB) + VTb (bf16 V^T,
  // second 8 MiB). Both dead before the final proj GEMM overwrites d_out.
  const size_t per = (size_t)NM * ND;
  u16* Qb = (u16*)d_ws;
  u16* Kb = Qb + per;
  u16* Vb = Kb + per;
  u16* Wb = Vb + per;              // 4 * ND*ND bf16, contiguous
  u16* Yb = Qb;                    // alias
  u16* xb = (u16*)d_out;
  u16* VTb = xb + per;

  // 0) fp32 -> bf16 for weights and x
  cvt_all<<<2048, 256, 0, stream>>>(Wq, Wk, Wv, Wp, x, Wb, xb);

  // 1) QKV projections, single fused dispatch (Q pre-scaled by QSCALE)
  gemm_qkv<<<dim3(3 * ND / BN, NM / BM), 256, 0, stream>>>(
      xb, Wb, bq, bk, bv, Qb, Kb, Vb);

  // 1b) V -> VT for async staging in attention
  vtrans<<<dim3(NL / 64, NB * NH), 256, 0, stream>>>(Vb, VTb);

  // 2) MFMA flash attention (Y aliases Q)
  attn_mfma<<<1024, 256, 0, stream>>>(Qb, Kb, VTb, m, Yb);

  // 3) Output projection (BN=64: 512 blocks)
  const u16* Wpb = Wb + 3 * (size_t)ND * ND;
  gemm_proj<<<dim3(ND / BN2, NM / BM), 256, 0, stream>>>(Yb, Wpb, bp, out);
}